// Round 7
// baseline (76.790 us; speedup 1.0000x reference)
//
#include <hip/hip_runtime.h>

#define NKC 256   // clusters (K)
#define ND  64    // feature dim (D)

using v8bf = __attribute__((ext_vector_type(8))) __bf16;
using v4f  = __attribute__((ext_vector_type(4))) float;
using v4u  = __attribute__((ext_vector_type(4))) unsigned int;

// Single fused kernel. Each block:
//  - converts clusters f32->bf16 into swizzled LDS (native casts -> compiler
//    emits v_cvt_pk_bf16_f32; hand-rolled rounding cost ~8x more VALU)
//  - x loads issued FIRST (nontemporal; HBM latency hides under staging)
//  - swapped-operand MFMA (D[row=cluster, col=x-row])
//  - LDS transpose epilogue -> full 1KB-contiguous nontemporal row stores
__global__ __launch_bounds__(256, 4)
void cluster_kernel(const float* __restrict__ x,
                    const float* __restrict__ clusters,
                    float* __restrict__ out) {
    __shared__ __align__(16) unsigned short sc[NKC * ND];   // 32 KB
    __shared__ float scsq[NKC];

    const int t    = threadIdx.x;
    const int lane = t & 63;
    const int wid  = t >> 6;        // wave in block (0..3)
    const int lr   = lane & 15;
    const int hi   = lane >> 4;     // 0..3
    const int kg   = hi << 3;       // k-offset within 32: 0,8,16,24

    // ---- issue this lane's x-row loads FIRST (nt: x is read exactly once)
    const int row = blockIdx.x * 64 + wid * 16 + lr;
    const float* xp = x + (size_t)row * ND + kg;
    v4f x00 = __builtin_nontemporal_load((const v4f*)(xp));
    v4f x01 = __builtin_nontemporal_load((const v4f*)(xp + 4));
    v4f x10 = __builtin_nontemporal_load((const v4f*)(xp + 32));
    v4f x11 = __builtin_nontemporal_load((const v4f*)(xp + 36));

    // ---- stage clusters: f32 -> bf16 swizzled LDS + per-row sumsq.
    // 4 iters; thread handles 16 floats (64B, coalesced) of cluster row
    // (it*64 + t/4), segment (t&3).
    {
        const int seg  = t & 3;
        const int rloc = t >> 2;
#pragma unroll
        for (int it = 0; it < 4; ++it) {
            const int crow = it * 64 + rloc;
            const float* cp = clusters + crow * ND + seg * 16;
            v4f c0 = *(const v4f*)(cp);
            v4f c1 = *(const v4f*)(cp + 4);
            v4f c2 = *(const v4f*)(cp + 8);
            v4f c3 = *(const v4f*)(cp + 12);
            float cv[16];
            *(v4f*)&cv[0] = c0; *(v4f*)&cv[4] = c1;
            *(v4f*)&cv[8] = c2; *(v4f*)&cv[12] = c3;
            float ss = 0.f;
#pragma unroll
            for (int i = 0; i < 16; ++i) ss += cv[i] * cv[i];
            ss += __shfl_xor(ss, 1);
            ss += __shfl_xor(ss, 2);
            if (seg == 0) scsq[crow] = ss;
            v8bf w0, w1;
#pragma unroll
            for (int i = 0; i < 8; ++i) {
                w0[i] = (__bf16)cv[i];        // -> v_cvt_pk_bf16_f32 pairs
                w1[i] = (__bf16)cv[8 + i];
            }
            const int swz = (crow & 7) << 4;
            const int byte0 = crow * 128 + seg * 32;
            *(v8bf*)((char*)sc + ( byte0       ^ swz)) = w0;
            *(v8bf*)((char*)sc + ((byte0 + 16) ^ swz)) = w1;
        }
    }
    __syncthreads();

    // ---- convert x (native casts), full-row sumsq
    float v0[8], v1[8];
    *(v4f*)&v0[0] = x00; *(v4f*)&v0[4] = x01;
    *(v4f*)&v1[0] = x10; *(v4f*)&v1[4] = x11;

    float p = 0.f;
#pragma unroll
    for (int i = 0; i < 8; ++i) p += v0[i] * v0[i] + v1[i] * v1[i];
    p += __shfl_xor(p, 16);
    p += __shfl_xor(p, 32);

    v8bf a0, a1;
#pragma unroll
    for (int i = 0; i < 8; ++i) {
        a0[i] = (__bf16)v0[i];   // x fragment (B operand), k 0..31
        a1[i] = (__bf16)v1[i];   // x fragment, k 32..63
    }

    // ---- MFMA: 16 cluster-tiles x (K=64 as 2 steps). A = clusters from LDS.
    v4f acc[16];
#pragma unroll
    for (int j = 0; j < 16; ++j) {
        const int brow = (j << 4) + lr;           // cluster row within tile
        const int bswz = (brow & 7) << 4;
        v8bf c0 = *(v8bf*)((char*)sc + ((brow * 128      + kg * 2) ^ bswz));
        v8bf c1 = *(v8bf*)((char*)sc + ((brow * 128 + 64 + kg * 2) ^ bswz));
        v4f c = {0.f, 0.f, 0.f, 0.f};
        c = __builtin_amdgcn_mfma_f32_16x16x32_bf16(c0, a0, c, 0, 0, 0);
        c = __builtin_amdgcn_mfma_f32_16x16x32_bf16(c1, a1, c, 0, 0, 0);
        acc[j] = c;   // D[row=cluster 16j+4hi+r, col=x-row lr] per lane
    }

    // ---- epilogue: u = 1/(1+d); normalize fully in registers
    float ps = 0.f;
#pragma unroll
    for (int j = 0; j < 16; ++j) {
        v4f cs = *(const v4f*)&scsq[(j << 4) + (hi << 2)];
#pragma unroll
        for (int r = 0; r < 4; ++r) {
            float d = p + cs[r] - 2.0f * acc[j][r];
            float u = __builtin_amdgcn_rcpf(1.0f + d);
            acc[j][r] = u;
            ps += u;
        }
    }
    ps += __shfl_xor(ps, 16);
    ps += __shfl_xor(ps, 32);
    const float inv = __builtin_amdgcn_rcpf(ps);
#pragma unroll
    for (int j = 0; j < 16; ++j) {
#pragma unroll
        for (int r = 0; r < 4; ++r) acc[j][r] *= inv;
    }

    // ---- all waves done reading sc -> reuse it as transpose scratch
    __syncthreads();

    // Per-wave 8KB slice; 2 rounds x 8 rows. Write swizzled, read back so
    // lane i holds cols [4i,4i+4) of one row -> 1KB contiguous nt store.
    char* slice = (char*)sc + wid * 8192;
    const int q = lr & 7;                 // row-local within round
    const int rowbase = blockIdx.x * 64 + wid * 16;
#pragma unroll
    for (int rnd = 0; rnd < 2; ++rnd) {
        if ((lr >> 3) == rnd) {
#pragma unroll
            for (int j = 0; j < 16; ++j) {
                *(v4u*)(slice + q * 1024 + (((j << 6) + (hi << 4)) ^ (q << 4))) =
                    *(v4u*)&acc[j];
            }
        }
        __asm__ volatile("s_waitcnt lgkmcnt(0)" ::: "memory");
#pragma unroll
        for (int q2 = 0; q2 < 8; ++q2) {
            v4u val = *(v4u*)(slice + q2 * 1024 + ((lane << 4) ^ (q2 << 4)));
            float* orow = out + (size_t)(rowbase + rnd * 8 + q2) * NKC;
            __builtin_nontemporal_store(val, (v4u*)(orow + (lane << 2)));
        }
        __asm__ volatile("s_waitcnt lgkmcnt(0)" ::: "memory");
    }
}

extern "C" void kernel_launch(void* const* d_in, const int* in_sizes, int n_in,
                              void* d_out, int out_size, void* d_ws, size_t ws_size,
                              hipStream_t stream) {
    const float* x        = (const float*)d_in[0];
    const float* clusters = (const float*)d_in[1];
    float* out = (float*)d_out;
    const int N = in_sizes[0] / ND;                 // 262144

    cluster_kernel<<<N / 64, 256, 0, stream>>>(x, clusters, out);
}

// Round 8
// 60.916 us; speedup vs baseline: 1.2606x; 1.2606x over previous
//
#include <hip/hip_runtime.h>

#define NKC 256   // clusters (K)
#define ND  64    // feature dim (D)

using v8bf = __attribute__((ext_vector_type(8))) __bf16;
using v4f  = __attribute__((ext_vector_type(4))) float;
using v4u  = __attribute__((ext_vector_type(4))) unsigned int;

// Single fused kernel (R6 structure). R8 = R6 + native bf16 casts ONLY
// (v_cvt_pk_bf16_f32 path); x loads are regular cached loads — R7's
// nontemporal x-loads caused ~4x sector re-fetch (4 separate 16B requests
// per 64B sector with no L2 allocation) and regressed 62->77us.
__global__ __launch_bounds__(256, 4)
void cluster_kernel(const float* __restrict__ x,
                    const float* __restrict__ clusters,
                    float* __restrict__ out) {
    __shared__ __align__(16) unsigned short sc[NKC * ND];   // 32 KB
    __shared__ float scsq[NKC];

    const int t    = threadIdx.x;
    const int lane = t & 63;
    const int wid  = t >> 6;        // wave in block (0..3)
    const int lr   = lane & 15;
    const int hi   = lane >> 4;     // 0..3
    const int kg   = hi << 3;       // k-offset within 32: 0,8,16,24

    // ---- issue this lane's x-row loads FIRST (HBM latency hides under staging)
    const int row = blockIdx.x * 64 + wid * 16 + lr;
    const float* xp = x + (size_t)row * ND + kg;
    v4f x00 = *(const v4f*)(xp);
    v4f x01 = *(const v4f*)(xp + 4);
    v4f x10 = *(const v4f*)(xp + 32);
    v4f x11 = *(const v4f*)(xp + 36);

    // ---- stage clusters: f32 -> bf16 swizzled LDS + per-row sumsq.
    // 4 iters; thread handles 16 floats (64B, coalesced) of cluster row
    // (it*64 + t/4), segment (t&3).
    {
        const int seg  = t & 3;
        const int rloc = t >> 2;
#pragma unroll
        for (int it = 0; it < 4; ++it) {
            const int crow = it * 64 + rloc;
            const float* cp = clusters + crow * ND + seg * 16;
            v4f c0 = *(const v4f*)(cp);
            v4f c1 = *(const v4f*)(cp + 4);
            v4f c2 = *(const v4f*)(cp + 8);
            v4f c3 = *(const v4f*)(cp + 12);
            float cv[16];
            *(v4f*)&cv[0] = c0; *(v4f*)&cv[4] = c1;
            *(v4f*)&cv[8] = c2; *(v4f*)&cv[12] = c3;
            float ss = 0.f;
#pragma unroll
            for (int i = 0; i < 16; ++i) ss += cv[i] * cv[i];
            ss += __shfl_xor(ss, 1);
            ss += __shfl_xor(ss, 2);
            if (seg == 0) scsq[crow] = ss;
            v8bf w0, w1;
#pragma unroll
            for (int i = 0; i < 8; ++i) {
                w0[i] = (__bf16)cv[i];        // -> v_cvt_pk_bf16_f32 pairs
                w1[i] = (__bf16)cv[8 + i];
            }
            const int swz = (crow & 7) << 4;
            const int byte0 = crow * 128 + seg * 32;
            *(v8bf*)((char*)sc + ( byte0       ^ swz)) = w0;
            *(v8bf*)((char*)sc + ((byte0 + 16) ^ swz)) = w1;
        }
    }
    __syncthreads();

    // ---- convert x (native casts), full-row sumsq
    float v0[8], v1[8];
    *(v4f*)&v0[0] = x00; *(v4f*)&v0[4] = x01;
    *(v4f*)&v1[0] = x10; *(v4f*)&v1[4] = x11;

    float p = 0.f;
#pragma unroll
    for (int i = 0; i < 8; ++i) p += v0[i] * v0[i] + v1[i] * v1[i];
    p += __shfl_xor(p, 16);
    p += __shfl_xor(p, 32);

    v8bf a0, a1;
#pragma unroll
    for (int i = 0; i < 8; ++i) {
        a0[i] = (__bf16)v0[i];   // x fragment (B operand), k 0..31
        a1[i] = (__bf16)v1[i];   // x fragment, k 32..63
    }

    // ---- MFMA: 16 cluster-tiles x (K=64 as 2 steps). A = clusters from LDS.
    v4f acc[16];
#pragma unroll
    for (int j = 0; j < 16; ++j) {
        const int brow = (j << 4) + lr;           // cluster row within tile
        const int bswz = (brow & 7) << 4;
        v8bf c0 = *(v8bf*)((char*)sc + ((brow * 128      + kg * 2) ^ bswz));
        v8bf c1 = *(v8bf*)((char*)sc + ((brow * 128 + 64 + kg * 2) ^ bswz));
        v4f c = {0.f, 0.f, 0.f, 0.f};
        c = __builtin_amdgcn_mfma_f32_16x16x32_bf16(c0, a0, c, 0, 0, 0);
        c = __builtin_amdgcn_mfma_f32_16x16x32_bf16(c1, a1, c, 0, 0, 0);
        acc[j] = c;   // D[row=cluster 16j+4hi+r, col=x-row lr] per lane
    }

    // ---- epilogue: u = 1/(1+d); normalize fully in registers
    float ps = 0.f;
#pragma unroll
    for (int j = 0; j < 16; ++j) {
        v4f cs = *(const v4f*)&scsq[(j << 4) + (hi << 2)];
#pragma unroll
        for (int r = 0; r < 4; ++r) {
            float d = p + cs[r] - 2.0f * acc[j][r];
            float u = __builtin_amdgcn_rcpf(1.0f + d);
            acc[j][r] = u;
            ps += u;
        }
    }
    ps += __shfl_xor(ps, 16);
    ps += __shfl_xor(ps, 32);
    const float inv = __builtin_amdgcn_rcpf(ps);
#pragma unroll
    for (int j = 0; j < 16; ++j) {
#pragma unroll
        for (int r = 0; r < 4; ++r) acc[j][r] *= inv;
    }

    // ---- all waves done reading sc -> reuse it as transpose scratch
    __syncthreads();

    // Per-wave 8KB slice; 2 rounds x 8 rows. Write swizzled, read back so
    // lane i holds cols [4i,4i+4) of one row -> 1KB contiguous nt store.
    char* slice = (char*)sc + wid * 8192;
    const int q = lr & 7;                 // row-local within round
    const int rowbase = blockIdx.x * 64 + wid * 16;
#pragma unroll
    for (int rnd = 0; rnd < 2; ++rnd) {
        if ((lr >> 3) == rnd) {
#pragma unroll
            for (int j = 0; j < 16; ++j) {
                *(v4u*)(slice + q * 1024 + (((j << 6) + (hi << 4)) ^ (q << 4))) =
                    *(v4u*)&acc[j];
            }
        }
        __asm__ volatile("s_waitcnt lgkmcnt(0)" ::: "memory");
#pragma unroll
        for (int q2 = 0; q2 < 8; ++q2) {
            v4u val = *(v4u*)(slice + q2 * 1024 + ((lane << 4) ^ (q2 << 4)));
            float* orow = out + (size_t)(rowbase + rnd * 8 + q2) * NKC;
            __builtin_nontemporal_store(val, (v4u*)(orow + (lane << 2)));
        }
        __asm__ volatile("s_waitcnt lgkmcnt(0)" ::: "memory");
    }
}

extern "C" void kernel_launch(void* const* d_in, const int* in_sizes, int n_in,
                              void* d_out, int out_size, void* d_ws, size_t ws_size,
                              hipStream_t stream) {
    const float* x        = (const float*)d_in[0];
    const float* clusters = (const float*)d_in[1];
    float* out = (float*)d_out;
    const int N = in_sizes[0] / ND;                 // 262144

    cluster_kernel<<<N / 64, 256, 0, stream>>>(x, clusters, out);
}

// Round 9
// 58.304 us; speedup vs baseline: 1.3171x; 1.0448x over previous
//
#include <hip/hip_runtime.h>

#define NKC 256   // clusters (K)
#define ND  64    // feature dim (D)

using v8bf = __attribute__((ext_vector_type(8))) __bf16;
using v4f  = __attribute__((ext_vector_type(4))) float;
using v4u  = __attribute__((ext_vector_type(4))) unsigned int;

// R9: 512-thread blocks (128 rows) — cluster staging amortized 2x vs R8,
// and the transpose uses a DEDICATED wave-private 4KB LDS slice, deleting
// the second __syncthreads (waves free-run from MFMA into stores).
//  - clusters f32->bf16 swizzled LDS via native casts (v_cvt_pk_bf16_f32)
//  - x loads issued first (cached; nt-loads caused 4x sector re-fetch in R7)
//  - swapped-operand MFMA (D[row=cluster, col=x-row])
//  - wave-private LDS transpose -> full 1KB-contiguous nontemporal row stores
__global__ __launch_bounds__(512, 4)
void cluster_kernel(const float* __restrict__ x,
                    const float* __restrict__ clusters,
                    float* __restrict__ out) {
    __shared__ __align__(16) unsigned short sc[NKC * ND];   // 32 KB clusters
    __shared__ float scsq[NKC];                             // 1 KB
    __shared__ __align__(16) float tsc[8 * 1024];           // 32 KB transpose, 4KB/wave

    const int t    = threadIdx.x;
    const int lane = t & 63;
    const int wid  = t >> 6;        // wave in block (0..7)
    const int lr   = lane & 15;
    const int hi   = lane >> 4;     // 0..3
    const int kg   = hi << 3;       // k-offset within 32: 0,8,16,24

    // ---- issue this lane's x-row loads FIRST (HBM latency hides under staging)
    const int row = blockIdx.x * 128 + wid * 16 + lr;
    const float* xp = x + (size_t)row * ND + kg;
    v4f x00 = *(const v4f*)(xp);
    v4f x01 = *(const v4f*)(xp + 4);
    v4f x10 = *(const v4f*)(xp + 32);
    v4f x11 = *(const v4f*)(xp + 36);

    // ---- stage clusters: f32 -> bf16 swizzled LDS + per-row sumsq.
    // 2 iters; thread handles 16 floats (64B, coalesced) of cluster row
    // (it*128 + t/4), segment (t&3).
    {
        const int seg  = t & 3;
        const int rloc = t >> 2;            // 0..127
#pragma unroll
        for (int it = 0; it < 2; ++it) {
            const int crow = it * 128 + rloc;
            const float* cp = clusters + crow * ND + seg * 16;
            v4f c0 = *(const v4f*)(cp);
            v4f c1 = *(const v4f*)(cp + 4);
            v4f c2 = *(const v4f*)(cp + 8);
            v4f c3 = *(const v4f*)(cp + 12);
            float cv[16];
            *(v4f*)&cv[0] = c0; *(v4f*)&cv[4] = c1;
            *(v4f*)&cv[8] = c2; *(v4f*)&cv[12] = c3;
            float ss = 0.f;
#pragma unroll
            for (int i = 0; i < 16; ++i) ss += cv[i] * cv[i];
            ss += __shfl_xor(ss, 1);
            ss += __shfl_xor(ss, 2);
            if (seg == 0) scsq[crow] = ss;
            v8bf w0, w1;
#pragma unroll
            for (int i = 0; i < 8; ++i) {
                w0[i] = (__bf16)cv[i];        // -> v_cvt_pk_bf16_f32 pairs
                w1[i] = (__bf16)cv[8 + i];
            }
            const int swz = (crow & 7) << 4;
            const int byte0 = crow * 128 + seg * 32;
            *(v8bf*)((char*)sc + ( byte0       ^ swz)) = w0;
            *(v8bf*)((char*)sc + ((byte0 + 16) ^ swz)) = w1;
        }
    }
    __syncthreads();   // the only barrier in the kernel

    // ---- convert x (native casts), full-row sumsq
    float v0[8], v1[8];
    *(v4f*)&v0[0] = x00; *(v4f*)&v0[4] = x01;
    *(v4f*)&v1[0] = x10; *(v4f*)&v1[4] = x11;

    float p = 0.f;
#pragma unroll
    for (int i = 0; i < 8; ++i) p += v0[i] * v0[i] + v1[i] * v1[i];
    p += __shfl_xor(p, 16);
    p += __shfl_xor(p, 32);

    v8bf a0, a1;
#pragma unroll
    for (int i = 0; i < 8; ++i) {
        a0[i] = (__bf16)v0[i];   // x fragment (B operand), k 0..31
        a1[i] = (__bf16)v1[i];   // x fragment, k 32..63
    }

    // ---- MFMA: 16 cluster-tiles x (K=64 as 2 steps). A = clusters from LDS.
    v4f acc[16];
#pragma unroll
    for (int j = 0; j < 16; ++j) {
        const int brow = (j << 4) + lr;           // cluster row within tile
        const int bswz = (brow & 7) << 4;
        v8bf c0 = *(v8bf*)((char*)sc + ((brow * 128      + kg * 2) ^ bswz));
        v8bf c1 = *(v8bf*)((char*)sc + ((brow * 128 + 64 + kg * 2) ^ bswz));
        v4f c = {0.f, 0.f, 0.f, 0.f};
        c = __builtin_amdgcn_mfma_f32_16x16x32_bf16(c0, a0, c, 0, 0, 0);
        c = __builtin_amdgcn_mfma_f32_16x16x32_bf16(c1, a1, c, 0, 0, 0);
        acc[j] = c;   // D[row=cluster 16j+4hi+r, col=x-row lr] per lane
    }

    // ---- epilogue: u = 1/(1+d); normalize fully in registers
    float ps = 0.f;
#pragma unroll
    for (int j = 0; j < 16; ++j) {
        v4f cs = *(const v4f*)&scsq[(j << 4) + (hi << 2)];
#pragma unroll
        for (int r = 0; r < 4; ++r) {
            float d = p + cs[r] - 2.0f * acc[j][r];
            float u = __builtin_amdgcn_rcpf(1.0f + d);
            acc[j][r] = u;
            ps += u;
        }
    }
    ps += __shfl_xor(ps, 16);
    ps += __shfl_xor(ps, 32);
    const float inv = __builtin_amdgcn_rcpf(ps);
#pragma unroll
    for (int j = 0; j < 16; ++j) {
#pragma unroll
        for (int r = 0; r < 4; ++r) acc[j][r] *= inv;
    }

    // ---- wave-private transpose (4KB slice, NO block barrier):
    // 4 rounds x 4 rows. Writer lane (lr=4*rnd+q, hi) places acc[j]
    // (= clusters 16j+4hi..+3 of x-row rowbase+lr) at q*1024 + ((j^q)*64 +
    // hi*16)  [canonical byte 64j+16hi stored at 64(j^q)+16hi: write-side
    // 2-way bank alias = free, read-side even]. Reader lane inverts with
    // j' = (lane>>2)^q2 and stores 1KB-contiguous rows (nt, full-line).
    char* slice = (char*)tsc + wid * 4096;
    const int q = lr & 3;                 // row-local within round
    const int rowbase = blockIdx.x * 128 + wid * 16;
#pragma unroll
    for (int rnd = 0; rnd < 4; ++rnd) {
        if ((lr >> 2) == rnd) {
#pragma unroll
            for (int j = 0; j < 16; ++j) {
                *(v4u*)(slice + q * 1024 + (((j ^ q) << 6) + (hi << 4))) =
                    *(v4u*)&acc[j];
            }
        }
        __asm__ volatile("s_waitcnt lgkmcnt(0)" ::: "memory");
#pragma unroll
        for (int q2 = 0; q2 < 4; ++q2) {
            v4u val = *(v4u*)(slice + q2 * 1024 +
                              ((((lane >> 2) ^ q2) << 6) + ((lane & 3) << 4)));
            float* orow = out + (size_t)(rowbase + rnd * 4 + q2) * NKC;
            __builtin_nontemporal_store(val, (v4u*)(orow + (lane << 2)));
        }
        __asm__ volatile("s_waitcnt lgkmcnt(0)" ::: "memory");  // WAR: next round reuses slice
    }
}

extern "C" void kernel_launch(void* const* d_in, const int* in_sizes, int n_in,
                              void* d_out, int out_size, void* d_ws, size_t ws_size,
                              hipStream_t stream) {
    const float* x        = (const float*)d_in[0];
    const float* clusters = (const float*)d_in[1];
    float* out = (float*)d_out;
    const int N = in_sizes[0] / ND;                 // 262144

    cluster_kernel<<<N / 128, 512, 0, stream>>>(x, clusters, out);
}